// Round 1
// baseline (546.895 us; speedup 1.0000x reference)
//
#include <hip/hip_runtime.h>

#define NN 50000
#define NE 800000
#define D 128

// ---------------- utility kernels ----------------

__global__ __launch_bounds__(256) void zero_i32(int* __restrict__ p, int n) {
  int i = blockIdx.x * blockDim.x + threadIdx.x;
  if (i < n) p[i] = 0;
}

__global__ __launch_bounds__(256) void deg_kernel(const int* __restrict__ src,
                                                  const int* __restrict__ dst,
                                                  int* __restrict__ deg_in,
                                                  int* __restrict__ deg_out, int E) {
  int e = blockIdx.x * blockDim.x + threadIdx.x;
  if (e < E) {
    atomicAdd(&deg_in[dst[e]], 1);
    atomicAdd(&deg_out[src[e]], 1);
  }
}

// single-block exclusive scan over n ints (wave-shuffle based)
__global__ __launch_bounds__(1024) void scan_kernel(const int* __restrict__ deg,
                                                    int* __restrict__ row_ptr, int n) {
  __shared__ int wsum[16];
  int lane = threadIdx.x & 63;
  int wid = threadIdx.x >> 6;
  int base = 0;
  for (int start = 0; start < n; start += 1024) {
    int i = start + threadIdx.x;
    int v = (i < n) ? deg[i] : 0;
    int incl = v;
#pragma unroll
    for (int off = 1; off < 64; off <<= 1) {
      int t = __shfl_up(incl, off);
      if (lane >= off) incl += t;
    }
    if (lane == 63) wsum[wid] = incl;
    __syncthreads();
    if (wid == 0) {
      int w = (lane < 16) ? wsum[lane] : 0;
#pragma unroll
      for (int off = 1; off < 16; off <<= 1) {
        int t = __shfl_up(w, off);
        if (lane >= off) w += t;
      }
      if (lane < 16) wsum[lane] = w;
    }
    __syncthreads();
    int woff = (wid > 0) ? wsum[wid - 1] : 0;
    int total = wsum[15];
    if (i < n) row_ptr[i] = base + woff + (incl - v);
    base += total;
    __syncthreads();  // protect wsum before next chunk
  }
  if (threadIdx.x == 0) row_ptr[n] = base;
}

__global__ __launch_bounds__(256) void fill_kernel(const int* __restrict__ src,
                                                   const int* __restrict__ dst,
                                                   const int* __restrict__ row_ptr,
                                                   int* __restrict__ cursor,
                                                   int* __restrict__ csr_src, int E) {
  int e = blockIdx.x * blockDim.x + threadIdx.x;
  if (e < E) {
    int d = dst[e];
    int pos = row_ptr[d] + atomicAdd(&cursor[d], 1);
    csr_src[pos] = src[e];
  }
}

// ---------------- aggregation: one wave per node ----------------
// MODE 0: sage  -> out = (sum_neigh + self) / (deg_in + 1)
// MODE 1: gcn   -> out = sum_neigh * rsqrt(max(deg_in,1))
template <int MODE>
__global__ __launch_bounds__(256) void agg_kernel(const float* __restrict__ h,
                                                  const int* __restrict__ row_ptr,
                                                  const int* __restrict__ csr_src,
                                                  const int* __restrict__ deg_in,
                                                  float* __restrict__ out, int N) {
  int wid = blockIdx.x * (blockDim.x >> 6) + (threadIdx.x >> 6);
  int lane = threadIdx.x & 63;
  if (wid >= N) return;
  int start = row_ptr[wid];
  int end = row_ptr[wid + 1];
  float2 acc = {0.f, 0.f};
  int idx_next = (start < end) ? csr_src[start] : 0;
  for (int e = start; e < end; ++e) {
    int idx = idx_next;
    if (e + 1 < end) idx_next = csr_src[e + 1];
    float2 v = ((const float2*)(h + (size_t)idx * D))[lane];
    acc.x += v.x;
    acc.y += v.y;
  }
  if (MODE == 0) {
    float2 self = ((const float2*)(h + (size_t)wid * D))[lane];
    float inv = 1.0f / (float)(deg_in[wid] + 1);
    acc.x = (acc.x + self.x) * inv;
    acc.y = (acc.y + self.y) * inv;
  } else {
    float s = rsqrtf(fmaxf((float)deg_in[wid], 1.0f));
    acc.x *= s;
    acc.y *= s;
  }
  ((float2*)(out + (size_t)wid * D))[lane] = acc;
}

// ---------------- GEMM: [N x 128] @ [128 x 128] + bias ----------------
// block: 256 threads; tile: 32 rows x 128 cols; thread: 4 rows x 4 cols
// MODE 0: out = A@W + b
// MODE 1: out = (A@W + b) * rsqrt(max(deg_out,1))   (per-row scale)
template <int MODE>
__global__ __launch_bounds__(256) void gemm_kernel(const float* __restrict__ A,
                                                   const float* __restrict__ W,
                                                   const float* __restrict__ bias,
                                                   const int* __restrict__ deg_out,
                                                   float* __restrict__ out, int N) {
  __shared__ float sW[D * D];
  __shared__ float sA[32][D];
  int tid = threadIdx.x;
  // stage W (16384 floats) as float4
  for (int i = tid; i < D * D / 4; i += 256) {
    ((float4*)sW)[i] = ((const float4*)W)[i];
  }
  int cg = tid & 31;  // col group: cols cg*4 .. cg*4+3
  int rg = tid >> 5;  // row group 0..7: rows rg*4 .. rg*4+3
  float4 bv = ((const float4*)bias)[cg];
  int row0 = blockIdx.x * 32;
  // stage A tile (32 rows x 128 cols) as float4
  for (int i = tid; i < 32 * 32; i += 256) {
    int r = i >> 5;
    int c4 = i & 31;
    int row = row0 + r;
    float4 v = make_float4(0.f, 0.f, 0.f, 0.f);
    if (row < N) v = ((const float4*)(A + (size_t)row * D))[c4];
    ((float4*)sA[r])[c4] = v;
  }
  __syncthreads();
  float acc[4][4];
#pragma unroll
  for (int r = 0; r < 4; ++r)
#pragma unroll
    for (int c = 0; c < 4; ++c) acc[r][c] = 0.f;

#pragma unroll 4
  for (int k = 0; k < D; ++k) {
    float4 w = *(const float4*)&sW[k * D + cg * 4];
#pragma unroll
    for (int r = 0; r < 4; ++r) {
      float a = sA[rg * 4 + r][k];
      acc[r][0] = fmaf(a, w.x, acc[r][0]);
      acc[r][1] = fmaf(a, w.y, acc[r][1]);
      acc[r][2] = fmaf(a, w.z, acc[r][2]);
      acc[r][3] = fmaf(a, w.w, acc[r][3]);
    }
  }

#pragma unroll
  for (int r = 0; r < 4; ++r) {
    int row = row0 + rg * 4 + r;
    if (row < N) {
      float scale = 1.0f;
      if (MODE == 1) scale = rsqrtf(fmaxf((float)deg_out[row], 1.0f));
      float4 o;
      o.x = (acc[r][0] + bv.x) * scale;
      o.y = (acc[r][1] + bv.y) * scale;
      o.z = (acc[r][2] + bv.z) * scale;
      o.w = (acc[r][3] + bv.w) * scale;
      ((float4*)(out + (size_t)row * D))[cg] = o;
    }
  }
}

// ---------------- launcher ----------------

extern "C" void kernel_launch(void* const* d_in, const int* in_sizes, int n_in,
                              void* d_out, int out_size, void* d_ws, size_t ws_size,
                              hipStream_t stream) {
  const float* x = (const float*)d_in[0];
  const float* W1 = (const float*)d_in[1];
  const float* b1 = (const float*)d_in[2];
  const float* W2 = (const float*)d_in[3];
  const float* b2 = (const float*)d_in[4];
  const float* W3 = (const float*)d_in[5];
  const float* b3 = (const float*)d_in[6];
  const int* src = (const int*)d_in[7];
  const int* dst = (const int*)d_in[8];
  float* out = (float*)d_out;

  const int N = NN, E = NE;

  // workspace layout: [bufA: N*128 f32][bufB: N*128 f32]
  //                   [deg_in: N][deg_out: N][cursor: N][row_ptr: N+1][csr_src: E]
  float* bufA = (float*)d_ws;
  float* bufB = bufA + (size_t)N * D;
  int* deg_in = (int*)(bufB + (size_t)N * D);
  int* deg_out = deg_in + N;
  int* cursor = deg_out + N;
  int* row_ptr = cursor + N;
  int* csr_src = row_ptr + N + 1;

  // zero deg_in, deg_out, cursor (contiguous 3N ints)
  zero_i32<<<(3 * N + 255) / 256, 256, 0, stream>>>(deg_in, 3 * N);
  deg_kernel<<<(E + 255) / 256, 256, 0, stream>>>(src, dst, deg_in, deg_out, E);
  scan_kernel<<<1, 1024, 0, stream>>>(deg_in, row_ptr, N);
  fill_kernel<<<(E + 255) / 256, 256, 0, stream>>>(src, dst, row_ptr, cursor, csr_src, E);

  int aggBlocks = (N + 3) / 4;       // 4 waves (nodes) per 256-thread block
  int gemmBlocks = (N + 31) / 32;    // 32 rows per block

  // layer 1: sage(x, W1, b1)
  agg_kernel<0><<<aggBlocks, 256, 0, stream>>>(x, row_ptr, csr_src, deg_in, bufA, N);
  gemm_kernel<0><<<gemmBlocks, 256, 0, stream>>>(bufA, W1, b1, deg_out, bufB, N);
  // layer 2: sage(h1, W2, b2), epilogue folds in norm_out scaling for layer 3
  agg_kernel<0><<<aggBlocks, 256, 0, stream>>>(bufB, row_ptr, csr_src, deg_in, bufA, N);
  gemm_kernel<1><<<gemmBlocks, 256, 0, stream>>>(bufA, W2, b2, deg_out, bufB, N);
  // layer 3: gcn: agg(h2*norm_out) * norm_in @ W3 + b3
  agg_kernel<1><<<aggBlocks, 256, 0, stream>>>(bufB, row_ptr, csr_src, deg_in, bufA, N);
  gemm_kernel<0><<<gemmBlocks, 256, 0, stream>>>(bufA, W3, b3, deg_out, out, N);
}

// Round 2
// 475.381 us; speedup vs baseline: 1.1504x; 1.1504x over previous
//
#include <hip/hip_runtime.h>

#define NN 50000
#define NE 800000
#define D 128

// ---------------- degree count ----------------

__global__ __launch_bounds__(256) void deg_kernel(const int* __restrict__ src,
                                                  const int* __restrict__ dst,
                                                  int* __restrict__ deg_in,
                                                  int* __restrict__ deg_out, int E) {
  int e = blockIdx.x * blockDim.x + threadIdx.x;
  if (e < E) {
    atomicAdd(&deg_in[dst[e]], 1);
    atomicAdd(&deg_out[src[e]], 1);
  }
}

// ---------------- 3-phase exclusive scan over deg_in -> row_ptr ----------------

// block-wide (256 thr) exclusive scan helper; returns exclusive prefix of v
__device__ __forceinline__ int block_excl_scan(int v, int* wsum) {
  int lane = threadIdx.x & 63;
  int w = threadIdx.x >> 6;
  int incl = v;
#pragma unroll
  for (int off = 1; off < 64; off <<= 1) {
    int t = __shfl_up(incl, off);
    if (lane >= off) incl += t;
  }
  if (lane == 63) wsum[w] = incl;
  __syncthreads();
  int wo = 0;
#pragma unroll
  for (int j = 0; j < 4; ++j)
    if (j < w) wo += wsum[j];
  return wo + incl - v;
}

__global__ __launch_bounds__(256) void scan1(const int* __restrict__ deg,
                                             int* __restrict__ partials, int N) {
  __shared__ int wsum[4];
  int i = blockIdx.x * 256 + threadIdx.x;
  int v = (i < N) ? deg[i] : 0;
  int excl = block_excl_scan(v, wsum);
  if (threadIdx.x == 255) partials[blockIdx.x] = excl + v;
}

__global__ __launch_bounds__(256) void scan2(int* __restrict__ partials, int nb) {
  __shared__ int wsum[4];
  int v = (threadIdx.x < nb) ? partials[threadIdx.x] : 0;
  int excl = block_excl_scan(v, wsum);
  if (threadIdx.x < nb) partials[threadIdx.x] = excl;
}

__global__ __launch_bounds__(256) void scan3(const int* __restrict__ deg,
                                             const int* __restrict__ partials,
                                             int* __restrict__ row_ptr, int N) {
  __shared__ int wsum[4];
  int i = blockIdx.x * 256 + threadIdx.x;
  int v = (i < N) ? deg[i] : 0;
  int excl = block_excl_scan(v, wsum);
  if (i < N) row_ptr[i] = partials[blockIdx.x] + excl;
  if (blockIdx.x == gridDim.x - 1 && threadIdx.x == 0) row_ptr[N] = NE;
}

__global__ __launch_bounds__(256) void fill_kernel(const int* __restrict__ src,
                                                   const int* __restrict__ dst,
                                                   const int* __restrict__ row_ptr,
                                                   int* __restrict__ cursor,
                                                   int* __restrict__ csr_src, int E) {
  int e = blockIdx.x * blockDim.x + threadIdx.x;
  if (e < E) {
    int d = dst[e];
    int pos = row_ptr[d] + atomicAdd(&cursor[d], 1);
    csr_src[pos] = src[e];
  }
}

// ---------------- aggregation: one wave per node, 4-deep pipelined gathers ----
// MODE 0: sage  -> out = (sum_neigh + self) / (deg_in + 1)
// MODE 1: gcn   -> out = sum_neigh * rsqrt(max(deg_in,1))
template <int MODE>
__global__ __launch_bounds__(256) void agg_kernel(const float* __restrict__ h,
                                                  const int* __restrict__ row_ptr,
                                                  const int* __restrict__ csr_src,
                                                  const int* __restrict__ deg_in,
                                                  float* __restrict__ out, int N) {
  int wid = blockIdx.x * 4 + (threadIdx.x >> 6);
  int lane = threadIdx.x & 63;
  if (wid >= N) return;
  int start = row_ptr[wid];
  int end = row_ptr[wid + 1];
  float2 a0 = {0.f, 0.f}, a1 = {0.f, 0.f}, a2 = {0.f, 0.f}, a3 = {0.f, 0.f};
  int e = start;
  // 4 independent gathers in flight per iteration
  for (; e + 4 <= end; e += 4) {
    int i0 = csr_src[e + 0];
    int i1 = csr_src[e + 1];
    int i2 = csr_src[e + 2];
    int i3 = csr_src[e + 3];
    float2 v0 = ((const float2*)(h + (size_t)i0 * D))[lane];
    float2 v1 = ((const float2*)(h + (size_t)i1 * D))[lane];
    float2 v2 = ((const float2*)(h + (size_t)i2 * D))[lane];
    float2 v3 = ((const float2*)(h + (size_t)i3 * D))[lane];
    a0.x += v0.x; a0.y += v0.y;
    a1.x += v1.x; a1.y += v1.y;
    a2.x += v2.x; a2.y += v2.y;
    a3.x += v3.x; a3.y += v3.y;
  }
  for (; e < end; ++e) {
    int i0 = csr_src[e];
    float2 v = ((const float2*)(h + (size_t)i0 * D))[lane];
    a0.x += v.x; a0.y += v.y;
  }
  float2 acc;
  acc.x = (a0.x + a1.x) + (a2.x + a3.x);
  acc.y = (a0.y + a1.y) + (a2.y + a3.y);
  if (MODE == 0) {
    float2 self = ((const float2*)(h + (size_t)wid * D))[lane];
    float inv = 1.0f / (float)(deg_in[wid] + 1);
    acc.x = (acc.x + self.x) * inv;
    acc.y = (acc.y + self.y) * inv;
  } else {
    float s = rsqrtf(fmaxf((float)deg_in[wid], 1.0f));
    acc.x *= s;
    acc.y *= s;
  }
  ((float2*)(out + (size_t)wid * D))[lane] = acc;
}

// ---------------- GEMM: [N x 128] @ [128 x 128] + bias ----------------
// block: 256 threads; tile: 64 rows x 128 cols; thread: 8 rows x 4 cols.
// K split into two 64-wide stages so LDS = 32KB (W half) + 16KB (A half) = 48KB.
// All LDS reads are ds_read_b128; A-reads broadcast (same addr across 32 lanes).
// MODE 0: out = A@W + b
// MODE 1: out = (A@W + b) * rsqrt(max(deg_out,1))   (per-row scale)
template <int MODE>
__global__ __launch_bounds__(256) void gemm_kernel(const float* __restrict__ A,
                                                   const float* __restrict__ W,
                                                   const float* __restrict__ bias,
                                                   const int* __restrict__ deg_out,
                                                   float* __restrict__ out, int N) {
  __shared__ float sW[64 * 128];  // 32KB: k-half of W, [k][c] layout
  __shared__ float sA[64 * 64];   // 16KB: [row][k_local]
  int tid = threadIdx.x;
  int cg = tid & 31;  // col group: cols cg*4 .. cg*4+3
  int rg = tid >> 5;  // row group 0..7: rows rg*8 .. rg*8+7
  int row0 = blockIdx.x * 64;

  float acc[8][4];
#pragma unroll
  for (int r = 0; r < 8; ++r)
#pragma unroll
    for (int c = 0; c < 4; ++c) acc[r][c] = 0.f;

  for (int kh = 0; kh < 2; ++kh) {
    // stage W k-half: 64*128 floats = 2048 float4, 8 per thread
    const float4* Wg = (const float4*)(W + kh * 64 * 128);
#pragma unroll
    for (int i = tid; i < 2048; i += 256) ((float4*)sW)[i] = Wg[i];
    // stage A half: 64 rows x 64 k = 1024 float4, 4 per thread
#pragma unroll
    for (int i = tid; i < 1024; i += 256) {
      int r = i >> 4;
      int c4 = i & 15;
      int row = row0 + r;
      float4 v = make_float4(0.f, 0.f, 0.f, 0.f);
      if (row < N) v = ((const float4*)(A + (size_t)row * D + kh * 64))[c4];
      ((float4*)sA)[i] = v;
    }
    __syncthreads();

#pragma unroll 4
    for (int k4 = 0; k4 < 16; ++k4) {
      float4 w0 = ((const float4*)sW)[(k4 * 4 + 0) * 32 + cg];
      float4 w1 = ((const float4*)sW)[(k4 * 4 + 1) * 32 + cg];
      float4 w2 = ((const float4*)sW)[(k4 * 4 + 2) * 32 + cg];
      float4 w3 = ((const float4*)sW)[(k4 * 4 + 3) * 32 + cg];
#pragma unroll
      for (int r = 0; r < 8; ++r) {
        float4 a = ((const float4*)sA)[(rg * 8 + r) * 16 + k4];
        acc[r][0] = fmaf(a.x, w0.x, acc[r][0]);
        acc[r][0] = fmaf(a.y, w1.x, acc[r][0]);
        acc[r][0] = fmaf(a.z, w2.x, acc[r][0]);
        acc[r][0] = fmaf(a.w, w3.x, acc[r][0]);
        acc[r][1] = fmaf(a.x, w0.y, acc[r][1]);
        acc[r][1] = fmaf(a.y, w1.y, acc[r][1]);
        acc[r][1] = fmaf(a.z, w2.y, acc[r][1]);
        acc[r][1] = fmaf(a.w, w3.y, acc[r][1]);
        acc[r][2] = fmaf(a.x, w0.z, acc[r][2]);
        acc[r][2] = fmaf(a.y, w1.z, acc[r][2]);
        acc[r][2] = fmaf(a.z, w2.z, acc[r][2]);
        acc[r][2] = fmaf(a.w, w3.z, acc[r][2]);
        acc[r][3] = fmaf(a.x, w0.w, acc[r][3]);
        acc[r][3] = fmaf(a.y, w1.w, acc[r][3]);
        acc[r][3] = fmaf(a.z, w2.w, acc[r][3]);
        acc[r][3] = fmaf(a.w, w3.w, acc[r][3]);
      }
    }
    __syncthreads();
  }

  float4 bv = ((const float4*)bias)[cg];
#pragma unroll
  for (int r = 0; r < 8; ++r) {
    int row = row0 + rg * 8 + r;
    if (row < N) {
      float scale = 1.0f;
      if (MODE == 1) scale = rsqrtf(fmaxf((float)deg_out[row], 1.0f));
      float4 o;
      o.x = (acc[r][0] + bv.x) * scale;
      o.y = (acc[r][1] + bv.y) * scale;
      o.z = (acc[r][2] + bv.z) * scale;
      o.w = (acc[r][3] + bv.w) * scale;
      ((float4*)(out + (size_t)row * D))[cg] = o;
    }
  }
}

// ---------------- launcher ----------------

extern "C" void kernel_launch(void* const* d_in, const int* in_sizes, int n_in,
                              void* d_out, int out_size, void* d_ws, size_t ws_size,
                              hipStream_t stream) {
  const float* x = (const float*)d_in[0];
  const float* W1 = (const float*)d_in[1];
  const float* b1 = (const float*)d_in[2];
  const float* W2 = (const float*)d_in[3];
  const float* b2 = (const float*)d_in[4];
  const float* W3 = (const float*)d_in[5];
  const float* b3 = (const float*)d_in[6];
  const int* src = (const int*)d_in[7];
  const int* dst = (const int*)d_in[8];
  float* out = (float*)d_out;

  const int N = NN, E = NE;

  // workspace layout: [bufA: N*128 f32][bufB: N*128 f32]
  //                   [deg_in: N][deg_out: N][cursor: N][row_ptr: N+1]
  //                   [partials: 256][csr_src: E]
  float* bufA = (float*)d_ws;
  float* bufB = bufA + (size_t)N * D;
  int* deg_in = (int*)(bufB + (size_t)N * D);
  int* deg_out = deg_in + N;
  int* cursor = deg_out + N;
  int* row_ptr = cursor + N;
  int* partials = row_ptr + N + 1;
  int* csr_src = partials + 256;

  const int scanBlocks = (N + 255) / 256;  // 196

  hipMemsetAsync(deg_in, 0, (size_t)3 * N * sizeof(int), stream);
  deg_kernel<<<(E + 255) / 256, 256, 0, stream>>>(src, dst, deg_in, deg_out, E);
  scan1<<<scanBlocks, 256, 0, stream>>>(deg_in, partials, N);
  scan2<<<1, 256, 0, stream>>>(partials, scanBlocks);
  scan3<<<scanBlocks, 256, 0, stream>>>(deg_in, partials, row_ptr, N);
  fill_kernel<<<(E + 255) / 256, 256, 0, stream>>>(src, dst, row_ptr, cursor, csr_src, E);

  int aggBlocks = (N + 3) / 4;     // 4 waves (nodes) per 256-thread block
  int gemmBlocks = (N + 63) / 64;  // 64 rows per block

  // layer 1: sage(x, W1, b1)
  agg_kernel<0><<<aggBlocks, 256, 0, stream>>>(x, row_ptr, csr_src, deg_in, bufA, N);
  gemm_kernel<0><<<gemmBlocks, 256, 0, stream>>>(bufA, W1, b1, deg_out, bufB, N);
  // layer 2: sage(h1, W2, b2); epilogue folds norm_out for layer 3
  agg_kernel<0><<<aggBlocks, 256, 0, stream>>>(bufB, row_ptr, csr_src, deg_in, bufA, N);
  gemm_kernel<1><<<gemmBlocks, 256, 0, stream>>>(bufA, W2, b2, deg_out, bufB, N);
  // layer 3: gcn: (agg(h2*norm_out) * norm_in) @ W3 + b3
  agg_kernel<1><<<aggBlocks, 256, 0, stream>>>(bufB, row_ptr, csr_src, deg_in, bufA, N);
  gemm_kernel<0><<<gemmBlocks, 256, 0, stream>>>(bufA, W3, b3, deg_out, out, N);
}

// Round 3
// 462.578 us; speedup vs baseline: 1.1823x; 1.0277x over previous
//
#include <hip/hip_runtime.h>

#define NN 50000
#define NE 800000
#define D 128

#define CH 32              // edge chunks
#define EPC (NE / CH)      // 25000 edges per chunk
#define RG 8               // node ranges
#define NPR (NN / RG)      // 6250 nodes per range

// ---------------- CSR build, no global atomics ----------------
// grid 256 = (chunk c = blockIdx>>3) x (range r = blockIdx&7)
// LDS histograms of dst (for CSR) and src (for out-degree).
__global__ __launch_bounds__(256) void hist_kernel(const int* __restrict__ src,
                                                   const int* __restrict__ dst,
                                                   int* __restrict__ partial_dst,
                                                   int* __restrict__ partial_src) {
  __shared__ int hd[NPR];
  __shared__ int hs[NPR];
  int tid = threadIdx.x;
  int c = blockIdx.x >> 3;
  int r = blockIdx.x & 7;
  int base = r * NPR;
  for (int i = tid; i < NPR; i += 256) { hd[i] = 0; hs[i] = 0; }
  __syncthreads();
  int e0 = c * EPC;
  for (int i = tid; i < EPC; i += 256) {
    int d = dst[e0 + i];
    int s = src[e0 + i];
    unsigned dr = (unsigned)(d - base);
    unsigned sr = (unsigned)(s - base);
    if (dr < NPR) atomicAdd(&hd[dr], 1);
    if (sr < NPR) atomicAdd(&hs[sr], 1);
  }
  __syncthreads();
  for (int i = tid; i < NPR; i += 256) {
    partial_dst[c * NN + base + i] = hd[i];
    partial_src[c * NN + base + i] = hs[i];
  }
}

// per node d: turn partial_dst[c][d] into exclusive prefix over chunks (in place),
// total in-degree -> degtmp[d]; total src count -> deg_out[d].
__global__ __launch_bounds__(256) void reduce_kernel(int* __restrict__ partial_dst,
                                                     const int* __restrict__ partial_src,
                                                     int* __restrict__ degtmp,
                                                     int* __restrict__ deg_out, int N) {
  int d = blockIdx.x * 256 + threadIdx.x;
  if (d >= N) return;
  int run = 0;
#pragma unroll
  for (int c = 0; c < CH; ++c) {
    int v = partial_dst[c * NN + d];
    partial_dst[c * NN + d] = run;
    run += v;
  }
  degtmp[d] = run;
  int ro = 0;
#pragma unroll
  for (int c = 0; c < CH; ++c) ro += partial_src[c * NN + d];
  deg_out[d] = ro;
}

// ---------------- 3-phase exclusive scan over degtmp -> row_ptr ----------------

__device__ __forceinline__ int block_excl_scan(int v, int* wsum) {
  int lane = threadIdx.x & 63;
  int w = threadIdx.x >> 6;
  int incl = v;
#pragma unroll
  for (int off = 1; off < 64; off <<= 1) {
    int t = __shfl_up(incl, off);
    if (lane >= off) incl += t;
  }
  if (lane == 63) wsum[w] = incl;
  __syncthreads();
  int wo = 0;
#pragma unroll
  for (int j = 0; j < 4; ++j)
    if (j < w) wo += wsum[j];
  return wo + incl - v;
}

__global__ __launch_bounds__(256) void scan1(const int* __restrict__ deg,
                                             int* __restrict__ partials, int N) {
  __shared__ int wsum[4];
  int i = blockIdx.x * 256 + threadIdx.x;
  int v = (i < N) ? deg[i] : 0;
  int excl = block_excl_scan(v, wsum);
  if (threadIdx.x == 255) partials[blockIdx.x] = excl + v;
}

__global__ __launch_bounds__(256) void scan2(int* __restrict__ partials, int nb) {
  __shared__ int wsum[4];
  int v = (threadIdx.x < nb) ? partials[threadIdx.x] : 0;
  int excl = block_excl_scan(v, wsum);
  if (threadIdx.x < nb) partials[threadIdx.x] = excl;
}

__global__ __launch_bounds__(256) void scan3(const int* __restrict__ deg,
                                             const int* __restrict__ partials,
                                             int* __restrict__ row_ptr, int N) {
  __shared__ int wsum[4];
  int i = blockIdx.x * 256 + threadIdx.x;
  int v = (i < N) ? deg[i] : 0;
  int excl = block_excl_scan(v, wsum);
  if (i < N) row_ptr[i] = partials[blockIdx.x] + excl;
  if (blockIdx.x == gridDim.x - 1 && threadIdx.x == 0) row_ptr[N] = NE;
}

// fill pass: same (chunk,range) decomposition; LDS cursor initialized to
// row_ptr[d] + (exclusive prefix of this chunk); ds_add_rtn gives position.
__global__ __launch_bounds__(256) void fill_kernel(const int* __restrict__ src,
                                                   const int* __restrict__ dst,
                                                   const int* __restrict__ row_ptr,
                                                   const int* __restrict__ partial_dst,
                                                   int* __restrict__ csr_src) {
  __shared__ int cur[NPR];
  int tid = threadIdx.x;
  int c = blockIdx.x >> 3;
  int r = blockIdx.x & 7;
  int base = r * NPR;
  for (int i = tid; i < NPR; i += 256)
    cur[i] = row_ptr[base + i] + partial_dst[c * NN + base + i];
  __syncthreads();
  int e0 = c * EPC;
  for (int i = tid; i < EPC; i += 256) {
    int d = dst[e0 + i];
    unsigned dr = (unsigned)(d - base);
    if (dr < NPR) {
      int pos = atomicAdd(&cur[dr], 1);
      csr_src[pos] = src[e0 + i];
    }
  }
}

// ---------------- aggregation: one wave per node, half-wave per edge ----------
// lane = sub(1b) x col(5b); each lane loads float4 (16B), 2 edges per wave-step,
// 4-deep unroll -> 8 edges / 4KB outstanding per wave.
// MODE 0: sage  -> out = (sum_neigh + self) / (in_deg + 1)
// MODE 1: gcn   -> out = sum_neigh * rsqrt(max(in_deg,1))
template <int MODE>
__global__ __launch_bounds__(256) void agg_kernel(const float* __restrict__ h,
                                                  const int* __restrict__ row_ptr,
                                                  const int* __restrict__ csr_src,
                                                  float* __restrict__ out, int N) {
  int wid = blockIdx.x * 4 + (threadIdx.x >> 6);
  int lane = threadIdx.x & 63;
  if (wid >= N) return;
  int start = row_ptr[wid];
  int end = row_ptr[wid + 1];
  int sub = lane >> 5;
  int col = lane & 31;
  float4 a0 = {0.f, 0.f, 0.f, 0.f}, a1 = a0, a2 = a0, a3 = a0;
  int e = start;
  for (; e + 8 <= end; e += 8) {
    int i0 = csr_src[e + 0 + sub];
    int i1 = csr_src[e + 2 + sub];
    int i2 = csr_src[e + 4 + sub];
    int i3 = csr_src[e + 6 + sub];
    float4 v0 = ((const float4*)(h + (size_t)i0 * D))[col];
    float4 v1 = ((const float4*)(h + (size_t)i1 * D))[col];
    float4 v2 = ((const float4*)(h + (size_t)i2 * D))[col];
    float4 v3 = ((const float4*)(h + (size_t)i3 * D))[col];
    a0.x += v0.x; a0.y += v0.y; a0.z += v0.z; a0.w += v0.w;
    a1.x += v1.x; a1.y += v1.y; a1.z += v1.z; a1.w += v1.w;
    a2.x += v2.x; a2.y += v2.y; a2.z += v2.z; a2.w += v2.w;
    a3.x += v3.x; a3.y += v3.y; a3.z += v3.z; a3.w += v3.w;
  }
  for (; e + 2 <= end; e += 2) {
    int i0 = csr_src[e + sub];
    float4 v = ((const float4*)(h + (size_t)i0 * D))[col];
    a0.x += v.x; a0.y += v.y; a0.z += v.z; a0.w += v.w;
  }
  if (e < end && sub == 0) {
    int i0 = csr_src[e];
    float4 v = ((const float4*)(h + (size_t)i0 * D))[col];
    a0.x += v.x; a0.y += v.y; a0.z += v.z; a0.w += v.w;
  }
  float4 acc;
  acc.x = (a0.x + a1.x) + (a2.x + a3.x);
  acc.y = (a0.y + a1.y) + (a2.y + a3.y);
  acc.z = (a0.z + a1.z) + (a2.z + a3.z);
  acc.w = (a0.w + a1.w) + (a2.w + a3.w);
  // cross-half reduce: after this, all lanes hold the full column sum
  acc.x += __shfl_xor(acc.x, 32);
  acc.y += __shfl_xor(acc.y, 32);
  acc.z += __shfl_xor(acc.z, 32);
  acc.w += __shfl_xor(acc.w, 32);
  int indeg = end - start;
  if (MODE == 0) {
    float4 self = ((const float4*)(h + (size_t)wid * D))[col];
    float inv = 1.0f / (float)(indeg + 1);
    acc.x = (acc.x + self.x) * inv;
    acc.y = (acc.y + self.y) * inv;
    acc.z = (acc.z + self.z) * inv;
    acc.w = (acc.w + self.w) * inv;
  } else {
    float s = rsqrtf(fmaxf((float)indeg, 1.0f));
    acc.x *= s; acc.y *= s; acc.z *= s; acc.w *= s;
  }
  if (sub == 0) ((float4*)(out + (size_t)wid * D))[col] = acc;
}

// ---------------- GEMM: [N x 128] @ [128 x 128] + bias ----------------
// block: 256 threads; tile: 64 rows x 128 cols; thread: 8 rows x 4 cols.
// MODE 0: out = A@W + b
// MODE 1: out = (A@W + b) * rsqrt(max(deg_out,1))
template <int MODE>
__global__ __launch_bounds__(256) void gemm_kernel(const float* __restrict__ A,
                                                   const float* __restrict__ W,
                                                   const float* __restrict__ bias,
                                                   const int* __restrict__ deg_out,
                                                   float* __restrict__ out, int N) {
  __shared__ float sW[64 * 128];
  __shared__ float sA[64 * 64];
  int tid = threadIdx.x;
  int cg = tid & 31;
  int rg = tid >> 5;
  int row0 = blockIdx.x * 64;

  float acc[8][4];
#pragma unroll
  for (int r = 0; r < 8; ++r)
#pragma unroll
    for (int c = 0; c < 4; ++c) acc[r][c] = 0.f;

  for (int kh = 0; kh < 2; ++kh) {
    const float4* Wg = (const float4*)(W + kh * 64 * 128);
#pragma unroll
    for (int i = tid; i < 2048; i += 256) ((float4*)sW)[i] = Wg[i];
#pragma unroll
    for (int i = tid; i < 1024; i += 256) {
      int r = i >> 4;
      int c4 = i & 15;
      int row = row0 + r;
      float4 v = make_float4(0.f, 0.f, 0.f, 0.f);
      if (row < N) v = ((const float4*)(A + (size_t)row * D + kh * 64))[c4];
      ((float4*)sA)[i] = v;
    }
    __syncthreads();

#pragma unroll 4
    for (int k4 = 0; k4 < 16; ++k4) {
      float4 w0 = ((const float4*)sW)[(k4 * 4 + 0) * 32 + cg];
      float4 w1 = ((const float4*)sW)[(k4 * 4 + 1) * 32 + cg];
      float4 w2 = ((const float4*)sW)[(k4 * 4 + 2) * 32 + cg];
      float4 w3 = ((const float4*)sW)[(k4 * 4 + 3) * 32 + cg];
#pragma unroll
      for (int r = 0; r < 8; ++r) {
        float4 a = ((const float4*)sA)[(rg * 8 + r) * 16 + k4];
        acc[r][0] = fmaf(a.x, w0.x, acc[r][0]);
        acc[r][0] = fmaf(a.y, w1.x, acc[r][0]);
        acc[r][0] = fmaf(a.z, w2.x, acc[r][0]);
        acc[r][0] = fmaf(a.w, w3.x, acc[r][0]);
        acc[r][1] = fmaf(a.x, w0.y, acc[r][1]);
        acc[r][1] = fmaf(a.y, w1.y, acc[r][1]);
        acc[r][1] = fmaf(a.z, w2.y, acc[r][1]);
        acc[r][1] = fmaf(a.w, w3.y, acc[r][1]);
        acc[r][2] = fmaf(a.x, w0.z, acc[r][2]);
        acc[r][2] = fmaf(a.y, w1.z, acc[r][2]);
        acc[r][2] = fmaf(a.z, w2.z, acc[r][2]);
        acc[r][2] = fmaf(a.w, w3.z, acc[r][2]);
        acc[r][3] = fmaf(a.x, w0.w, acc[r][3]);
        acc[r][3] = fmaf(a.y, w1.w, acc[r][3]);
        acc[r][3] = fmaf(a.z, w2.w, acc[r][3]);
        acc[r][3] = fmaf(a.w, w3.w, acc[r][3]);
      }
    }
    __syncthreads();
  }

  float4 bv = ((const float4*)bias)[cg];
#pragma unroll
  for (int r = 0; r < 8; ++r) {
    int row = row0 + rg * 8 + r;
    if (row < N) {
      float scale = 1.0f;
      if (MODE == 1) scale = rsqrtf(fmaxf((float)deg_out[row], 1.0f));
      float4 o;
      o.x = (acc[r][0] + bv.x) * scale;
      o.y = (acc[r][1] + bv.y) * scale;
      o.z = (acc[r][2] + bv.z) * scale;
      o.w = (acc[r][3] + bv.w) * scale;
      ((float4*)(out + (size_t)row * D))[cg] = o;
    }
  }
}

// ---------------- launcher ----------------

extern "C" void kernel_launch(void* const* d_in, const int* in_sizes, int n_in,
                              void* d_out, int out_size, void* d_ws, size_t ws_size,
                              hipStream_t stream) {
  const float* x = (const float*)d_in[0];
  const float* W1 = (const float*)d_in[1];
  const float* b1 = (const float*)d_in[2];
  const float* W2 = (const float*)d_in[3];
  const float* b2 = (const float*)d_in[4];
  const float* W3 = (const float*)d_in[5];
  const float* b3 = (const float*)d_in[6];
  const int* src = (const int*)d_in[7];
  const int* dst = (const int*)d_in[8];
  float* out = (float*)d_out;

  const int N = NN, E = NE;

  // workspace layout
  float* bufA = (float*)d_ws;                          // N*D
  float* bufB = bufA + (size_t)N * D;                  // N*D
  int* partial_dst = (int*)(bufB + (size_t)N * D);     // CH*N
  int* partial_src = partial_dst + (size_t)CH * N;     // CH*N
  int* degtmp = partial_src + (size_t)CH * N;          // N
  int* deg_out = degtmp + N;                           // N
  int* row_ptr = deg_out + N;                          // N+1
  int* partials = row_ptr + N + 1;                     // 256
  int* csr_src = partials + 256;                       // E

  const int scanBlocks = (N + 255) / 256;  // 196

  hist_kernel<<<CH * RG, 256, 0, stream>>>(src, dst, partial_dst, partial_src);
  reduce_kernel<<<scanBlocks, 256, 0, stream>>>(partial_dst, partial_src, degtmp, deg_out, N);
  scan1<<<scanBlocks, 256, 0, stream>>>(degtmp, partials, N);
  scan2<<<1, 256, 0, stream>>>(partials, scanBlocks);
  scan3<<<scanBlocks, 256, 0, stream>>>(degtmp, partials, row_ptr, N);
  fill_kernel<<<CH * RG, 256, 0, stream>>>(src, dst, row_ptr, partial_dst, csr_src);

  int aggBlocks = (N + 3) / 4;
  int gemmBlocks = (N + 63) / 64;

  // layer 1: sage(x, W1, b1)
  agg_kernel<0><<<aggBlocks, 256, 0, stream>>>(x, row_ptr, csr_src, bufA, N);
  gemm_kernel<0><<<gemmBlocks, 256, 0, stream>>>(bufA, W1, b1, deg_out, bufB, N);
  // layer 2: sage(h1, W2, b2); epilogue folds norm_out for layer 3
  agg_kernel<0><<<aggBlocks, 256, 0, stream>>>(bufB, row_ptr, csr_src, bufA, N);
  gemm_kernel<1><<<gemmBlocks, 256, 0, stream>>>(bufA, W2, b2, deg_out, bufB, N);
  // layer 3: gcn: (agg(h2*norm_out) * norm_in) @ W3 + b3
  agg_kernel<1><<<aggBlocks, 256, 0, stream>>>(bufB, row_ptr, csr_src, bufA, N);
  gemm_kernel<0><<<gemmBlocks, 256, 0, stream>>>(bufA, W3, b3, deg_out, out, N);
}

// Round 4
// 357.865 us; speedup vs baseline: 1.5282x; 1.2926x over previous
//
#include <hip/hip_runtime.h>

#define NN 50000
#define NE 800000
#define D 128

#define CH 64              // edge chunks
#define EPC (NE / CH)      // 12500 edges per chunk
#define RG 8               // node ranges
#define NPR (NN / RG)      // 6250 nodes per range

// ---------------- bf16 helpers ----------------

__device__ __forceinline__ unsigned bf16rne(float f) {
  unsigned u = __float_as_uint(f);
  return (u + 0x7fffu + ((u >> 16) & 1u)) >> 16;
}
__device__ __forceinline__ unsigned packbf(float lo, float hi) {
  return bf16rne(lo) | (bf16rne(hi) << 16);
}

// convert f32 -> bf16 table (4 elems/thread)
__global__ __launch_bounds__(256) void cvt_kernel(const float* __restrict__ x,
                                                  unsigned short* __restrict__ xb, int n4) {
  int i = blockIdx.x * 256 + threadIdx.x;
  if (i < n4) {
    float4 v = ((const float4*)x)[i];
    uint2 p;
    p.x = packbf(v.x, v.y);
    p.y = packbf(v.z, v.w);
    ((uint2*)xb)[i] = p;
  }
}

// ---------------- CSR build, no global atomics ----------------
// grid CH*RG: (chunk c = blockIdx>>3) x (range r = blockIdx&7), 1024 threads.
__global__ __launch_bounds__(1024) void hist_kernel(const int* __restrict__ src,
                                                    const int* __restrict__ dst,
                                                    int* __restrict__ partial_dst,
                                                    int* __restrict__ partial_src) {
  __shared__ int hd[NPR];
  __shared__ int hs[NPR];
  int tid = threadIdx.x;
  int c = blockIdx.x >> 3;
  int r = blockIdx.x & 7;
  int base = r * NPR;
  for (int i = tid; i < NPR; i += 1024) { hd[i] = 0; hs[i] = 0; }
  __syncthreads();
  int e0 = c * EPC;
  for (int i = tid; i < EPC; i += 1024) {
    int d = dst[e0 + i];
    int s = src[e0 + i];
    unsigned dr = (unsigned)(d - base);
    unsigned sr = (unsigned)(s - base);
    if (dr < NPR) atomicAdd(&hd[dr], 1);
    if (sr < NPR) atomicAdd(&hs[sr], 1);
  }
  __syncthreads();
  for (int i = tid; i < NPR; i += 1024) {
    partial_dst[c * NN + base + i] = hd[i];
    partial_src[c * NN + base + i] = hs[i];
  }
}

// per node: exclusive prefix of partial_dst over chunks (in place), in-degree
// -> degtmp, out-degree -> deg_out.
__global__ __launch_bounds__(256) void reduce_kernel(int* __restrict__ partial_dst,
                                                     const int* __restrict__ partial_src,
                                                     int* __restrict__ degtmp,
                                                     int* __restrict__ deg_out, int N) {
  int d = blockIdx.x * 256 + threadIdx.x;
  if (d >= N) return;
  int run = 0;
#pragma unroll
  for (int c = 0; c < CH; ++c) {
    int v = partial_dst[c * NN + d];
    partial_dst[c * NN + d] = run;
    run += v;
  }
  degtmp[d] = run;
  int ro = 0;
#pragma unroll
  for (int c = 0; c < CH; ++c) ro += partial_src[c * NN + d];
  deg_out[d] = ro;
}

// ---------------- 3-phase exclusive scan over degtmp -> row_ptr --------------

__device__ __forceinline__ int block_excl_scan(int v, int* wsum) {
  int lane = threadIdx.x & 63;
  int w = threadIdx.x >> 6;
  int incl = v;
#pragma unroll
  for (int off = 1; off < 64; off <<= 1) {
    int t = __shfl_up(incl, off);
    if (lane >= off) incl += t;
  }
  if (lane == 63) wsum[w] = incl;
  __syncthreads();
  int wo = 0;
#pragma unroll
  for (int j = 0; j < 4; ++j)
    if (j < w) wo += wsum[j];
  return wo + incl - v;
}

__global__ __launch_bounds__(256) void scan1(const int* __restrict__ deg,
                                             int* __restrict__ partials, int N) {
  __shared__ int wsum[4];
  int i = blockIdx.x * 256 + threadIdx.x;
  int v = (i < N) ? deg[i] : 0;
  int excl = block_excl_scan(v, wsum);
  if (threadIdx.x == 255) partials[blockIdx.x] = excl + v;
}

__global__ __launch_bounds__(256) void scan2(int* __restrict__ partials, int nb) {
  __shared__ int wsum[4];
  int v = (threadIdx.x < nb) ? partials[threadIdx.x] : 0;
  int excl = block_excl_scan(v, wsum);
  if (threadIdx.x < nb) partials[threadIdx.x] = excl;
}

__global__ __launch_bounds__(256) void scan3(const int* __restrict__ deg,
                                             const int* __restrict__ partials,
                                             int* __restrict__ row_ptr, int N) {
  __shared__ int wsum[4];
  int i = blockIdx.x * 256 + threadIdx.x;
  int v = (i < N) ? deg[i] : 0;
  int excl = block_excl_scan(v, wsum);
  if (i < N) row_ptr[i] = partials[blockIdx.x] + excl;
  if (blockIdx.x == gridDim.x - 1 && threadIdx.x == 0) row_ptr[N] = NE;
}

// fill: LDS cursor = row_ptr + per-chunk exclusive offset; plain stores.
__global__ __launch_bounds__(1024) void fill_kernel(const int* __restrict__ src,
                                                    const int* __restrict__ dst,
                                                    const int* __restrict__ row_ptr,
                                                    const int* __restrict__ partial_dst,
                                                    int* __restrict__ csr_src) {
  __shared__ int cur[NPR];
  int tid = threadIdx.x;
  int c = blockIdx.x >> 3;
  int r = blockIdx.x & 7;
  int base = r * NPR;
  for (int i = tid; i < NPR; i += 1024)
    cur[i] = row_ptr[base + i] + partial_dst[c * NN + base + i];
  __syncthreads();
  int e0 = c * EPC;
  for (int i = tid; i < EPC; i += 1024) {
    int d = dst[e0 + i];
    unsigned dr = (unsigned)(d - base);
    if (dr < NPR) {
      int pos = atomicAdd(&cur[dr], 1);
      csr_src[pos] = src[e0 + i];
    }
  }
}

// ---------------- aggregation: one wave per node, quarter-wave per edge ------
// Gather table is bf16: row = 256B = 16 lanes x 16B. lane = q(2b) x col(4b).
// 4 edges per wave-load, 4-deep unroll -> 16 edges / 4KB in flight per wave.
// Accumulate f32 (8 per lane). MODE 0: sage (self+avg). MODE 1: gcn rsqrt.
__device__ __forceinline__ void bacc(float* a, uint4 u) {
  a[0] += __uint_as_float(u.x << 16);
  a[1] += __uint_as_float(u.x & 0xffff0000u);
  a[2] += __uint_as_float(u.y << 16);
  a[3] += __uint_as_float(u.y & 0xffff0000u);
  a[4] += __uint_as_float(u.z << 16);
  a[5] += __uint_as_float(u.z & 0xffff0000u);
  a[6] += __uint_as_float(u.w << 16);
  a[7] += __uint_as_float(u.w & 0xffff0000u);
}

template <int MODE>
__global__ __launch_bounds__(256) void agg_kernel(const unsigned short* __restrict__ hb,
                                                  const int* __restrict__ row_ptr,
                                                  const int* __restrict__ csr_src,
                                                  float* __restrict__ out, int N) {
  int wid = blockIdx.x * 4 + (threadIdx.x >> 6);
  int lane = threadIdx.x & 63;
  if (wid >= N) return;
  int start = row_ptr[wid];
  int end = row_ptr[wid + 1];
  int q = lane >> 4;    // 0..3: which edge in the 4-group
  int col = lane & 15;  // 16B granule within row
  float a0[8] = {0, 0, 0, 0, 0, 0, 0, 0};
  float a1[8] = {0, 0, 0, 0, 0, 0, 0, 0};
  float a2[8] = {0, 0, 0, 0, 0, 0, 0, 0};
  float a3[8] = {0, 0, 0, 0, 0, 0, 0, 0};
  int e = start;
  for (; e + 16 <= end; e += 16) {
    int i0 = csr_src[e + q];
    int i1 = csr_src[e + 4 + q];
    int i2 = csr_src[e + 8 + q];
    int i3 = csr_src[e + 12 + q];
    uint4 u0 = ((const uint4*)(hb + (size_t)i0 * D))[col];
    uint4 u1 = ((const uint4*)(hb + (size_t)i1 * D))[col];
    uint4 u2 = ((const uint4*)(hb + (size_t)i2 * D))[col];
    uint4 u3 = ((const uint4*)(hb + (size_t)i3 * D))[col];
    bacc(a0, u0);
    bacc(a1, u1);
    bacc(a2, u2);
    bacc(a3, u3);
  }
  for (; e + 4 <= end; e += 4) {
    int i0 = csr_src[e + q];
    uint4 u0 = ((const uint4*)(hb + (size_t)i0 * D))[col];
    bacc(a0, u0);
  }
  if (q < end - e) {
    int i0 = csr_src[e + q];
    uint4 u0 = ((const uint4*)(hb + (size_t)i0 * D))[col];
    bacc(a0, u0);
  }
#pragma unroll
  for (int j = 0; j < 8; ++j) a0[j] = (a0[j] + a1[j]) + (a2[j] + a3[j]);
  // cross-quarter reduce: lanes with same col end up with the full column sum
#pragma unroll
  for (int j = 0; j < 8; ++j) {
    a0[j] += __shfl_xor(a0[j], 16);
    a0[j] += __shfl_xor(a0[j], 32);
  }
  int indeg = end - start;
  if (MODE == 0) {
    uint4 s = ((const uint4*)(hb + (size_t)wid * D))[col];
    float sf[8] = {0, 0, 0, 0, 0, 0, 0, 0};
    bacc(sf, s);
    float inv = 1.0f / (float)(indeg + 1);
#pragma unroll
    for (int j = 0; j < 8; ++j) a0[j] = (a0[j] + sf[j]) * inv;
  } else {
    float sc = rsqrtf(fmaxf((float)indeg, 1.0f));
#pragma unroll
    for (int j = 0; j < 8; ++j) a0[j] *= sc;
  }
  if (q == 0) {
    float4 o0 = {a0[0], a0[1], a0[2], a0[3]};
    float4 o1 = {a0[4], a0[5], a0[6], a0[7]};
    ((float4*)(out + (size_t)wid * D))[col * 2] = o0;
    ((float4*)(out + (size_t)wid * D))[col * 2 + 1] = o1;
  }
}

// ---------------- GEMM: [N x 128] @ [128 x 128] + bias ----------------
// block 256; tile 64x128; thread 8 rows x 4 cols. f32 compute.
// MODE 1: scale rows by rsqrt(max(deg_out,1)). BFOUT 1: write bf16 table.
template <int MODE, int BFOUT>
__global__ __launch_bounds__(256) void gemm_kernel(const float* __restrict__ A,
                                                   const float* __restrict__ W,
                                                   const float* __restrict__ bias,
                                                   const int* __restrict__ deg_out,
                                                   float* __restrict__ outf,
                                                   unsigned short* __restrict__ outb, int N) {
  __shared__ float sW[64 * 128];
  __shared__ float sA[64 * 64];
  int tid = threadIdx.x;
  int cg = tid & 31;
  int rg = tid >> 5;
  int row0 = blockIdx.x * 64;

  float acc[8][4];
#pragma unroll
  for (int r = 0; r < 8; ++r)
#pragma unroll
    for (int c = 0; c < 4; ++c) acc[r][c] = 0.f;

  for (int kh = 0; kh < 2; ++kh) {
    const float4* Wg = (const float4*)(W + kh * 64 * 128);
#pragma unroll
    for (int i = tid; i < 2048; i += 256) ((float4*)sW)[i] = Wg[i];
#pragma unroll
    for (int i = tid; i < 1024; i += 256) {
      int r = i >> 4;
      int c4 = i & 15;
      int row = row0 + r;
      float4 v = make_float4(0.f, 0.f, 0.f, 0.f);
      if (row < N) v = ((const float4*)(A + (size_t)row * D + kh * 64))[c4];
      ((float4*)sA)[i] = v;
    }
    __syncthreads();

#pragma unroll 4
    for (int k4 = 0; k4 < 16; ++k4) {
      float4 w0 = ((const float4*)sW)[(k4 * 4 + 0) * 32 + cg];
      float4 w1 = ((const float4*)sW)[(k4 * 4 + 1) * 32 + cg];
      float4 w2 = ((const float4*)sW)[(k4 * 4 + 2) * 32 + cg];
      float4 w3 = ((const float4*)sW)[(k4 * 4 + 3) * 32 + cg];
#pragma unroll
      for (int r = 0; r < 8; ++r) {
        float4 a = ((const float4*)sA)[(rg * 8 + r) * 16 + k4];
        acc[r][0] = fmaf(a.x, w0.x, acc[r][0]);
        acc[r][0] = fmaf(a.y, w1.x, acc[r][0]);
        acc[r][0] = fmaf(a.z, w2.x, acc[r][0]);
        acc[r][0] = fmaf(a.w, w3.x, acc[r][0]);
        acc[r][1] = fmaf(a.x, w0.y, acc[r][1]);
        acc[r][1] = fmaf(a.y, w1.y, acc[r][1]);
        acc[r][1] = fmaf(a.z, w2.y, acc[r][1]);
        acc[r][1] = fmaf(a.w, w3.y, acc[r][1]);
        acc[r][2] = fmaf(a.x, w0.z, acc[r][2]);
        acc[r][2] = fmaf(a.y, w1.z, acc[r][2]);
        acc[r][2] = fmaf(a.z, w2.z, acc[r][2]);
        acc[r][2] = fmaf(a.w, w3.z, acc[r][2]);
        acc[r][3] = fmaf(a.x, w0.w, acc[r][3]);
        acc[r][3] = fmaf(a.y, w1.w, acc[r][3]);
        acc[r][3] = fmaf(a.z, w2.w, acc[r][3]);
        acc[r][3] = fmaf(a.w, w3.w, acc[r][3]);
      }
    }
    __syncthreads();
  }

  float4 bv = ((const float4*)bias)[cg];
#pragma unroll
  for (int r = 0; r < 8; ++r) {
    int row = row0 + rg * 8 + r;
    if (row < N) {
      float scale = 1.0f;
      if (MODE == 1) scale = rsqrtf(fmaxf((float)deg_out[row], 1.0f));
      float4 o;
      o.x = (acc[r][0] + bv.x) * scale;
      o.y = (acc[r][1] + bv.y) * scale;
      o.z = (acc[r][2] + bv.z) * scale;
      o.w = (acc[r][3] + bv.w) * scale;
      if (BFOUT) {
        uint2 p;
        p.x = packbf(o.x, o.y);
        p.y = packbf(o.z, o.w);
        ((uint2*)(outb + (size_t)row * D))[cg] = p;
      } else {
        ((float4*)(outf + (size_t)row * D))[cg] = o;
      }
    }
  }
}

// ---------------- launcher ----------------

extern "C" void kernel_launch(void* const* d_in, const int* in_sizes, int n_in,
                              void* d_out, int out_size, void* d_ws, size_t ws_size,
                              hipStream_t stream) {
  const float* x = (const float*)d_in[0];
  const float* W1 = (const float*)d_in[1];
  const float* b1 = (const float*)d_in[2];
  const float* W2 = (const float*)d_in[3];
  const float* b2 = (const float*)d_in[4];
  const float* W3 = (const float*)d_in[5];
  const float* b3 = (const float*)d_in[6];
  const int* src = (const int*)d_in[7];
  const int* dst = (const int*)d_in[8];
  float* out = (float*)d_out;

  const int N = NN, E = NE;

  // workspace layout (~68 MB)
  float* bufA = (float*)d_ws;                              // N*D f32
  unsigned short* hbf = (unsigned short*)(bufA + (size_t)N * D);  // N*D bf16
  int* partial_dst = (int*)(hbf + (size_t)N * D);          // CH*N
  int* partial_src = partial_dst + (size_t)CH * N;         // CH*N
  int* degtmp = partial_src + (size_t)CH * N;              // N
  int* deg_out = degtmp + N;                               // N
  int* row_ptr = deg_out + N;                              // N+1
  int* partials = row_ptr + N + 1;                         // 256
  int* csr_src = partials + 256;                           // E

  const int scanBlocks = (N + 255) / 256;  // 196

  cvt_kernel<<<(N * D / 4 + 255) / 256, 256, 0, stream>>>(x, hbf, N * D / 4);
  hist_kernel<<<CH * RG, 1024, 0, stream>>>(src, dst, partial_dst, partial_src);
  reduce_kernel<<<scanBlocks, 256, 0, stream>>>(partial_dst, partial_src, degtmp, deg_out, N);
  scan1<<<scanBlocks, 256, 0, stream>>>(degtmp, partials, N);
  scan2<<<1, 256, 0, stream>>>(partials, scanBlocks);
  scan3<<<scanBlocks, 256, 0, stream>>>(degtmp, partials, row_ptr, N);
  fill_kernel<<<CH * RG, 1024, 0, stream>>>(src, dst, row_ptr, partial_dst, csr_src);

  int aggBlocks = (N + 3) / 4;
  int gemmBlocks = (N + 63) / 64;

  // layer 1: sage(x)
  agg_kernel<0><<<aggBlocks, 256, 0, stream>>>(hbf, row_ptr, csr_src, bufA, N);
  gemm_kernel<0, 1><<<gemmBlocks, 256, 0, stream>>>(bufA, W1, b1, deg_out, nullptr, hbf, N);
  // layer 2: sage(h1); fold norm_out for layer 3 into epilogue
  agg_kernel<0><<<aggBlocks, 256, 0, stream>>>(hbf, row_ptr, csr_src, bufA, N);
  gemm_kernel<1, 1><<<gemmBlocks, 256, 0, stream>>>(bufA, W2, b2, deg_out, nullptr, hbf, N);
  // layer 3: gcn: (agg(h2*norm_out) * norm_in) @ W3 + b3
  agg_kernel<1><<<aggBlocks, 256, 0, stream>>>(hbf, row_ptr, csr_src, bufA, N);
  gemm_kernel<0, 0><<<gemmBlocks, 256, 0, stream>>>(bufA, W3, b3, deg_out, out, nullptr, N);
}

// Round 5
// 284.824 us; speedup vs baseline: 1.9201x; 1.2564x over previous
//
#include <hip/hip_runtime.h>

#define NN 50000
#define NE 800000
#define D 128

#define CH 64              // edge chunks
#define EPC (NE / CH)      // 12500 edges per chunk
#define RG 8               // node ranges
#define NPR (NN / RG)      // 6250 nodes per range

typedef short bf16x8 __attribute__((ext_vector_type(8)));
typedef float f32x4 __attribute__((ext_vector_type(4)));

// ---------------- bf16 helpers ----------------

__device__ __forceinline__ unsigned bf16rne(float f) {
  unsigned u = __float_as_uint(f);
  return (u + 0x7fffu + ((u >> 16) & 1u)) >> 16;
}
__device__ __forceinline__ unsigned packbf(float lo, float hi) {
  return bf16rne(lo) | (bf16rne(hi) << 16);
}

// convert f32 -> bf16 table (4 elems/thread)
__global__ __launch_bounds__(256) void cvt_kernel(const float* __restrict__ x,
                                                  unsigned short* __restrict__ xb, int n4) {
  int i = blockIdx.x * 256 + threadIdx.x;
  if (i < n4) {
    float4 v = ((const float4*)x)[i];
    uint2 p;
    p.x = packbf(v.x, v.y);
    p.y = packbf(v.z, v.w);
    ((uint2*)xb)[i] = p;
  }
}

// transpose + bf16-convert the three 128x128 weight matrices: WT[n][k] = W[k][n]
__global__ __launch_bounds__(256) void wcvt_kernel(const float* __restrict__ W1,
                                                   const float* __restrict__ W2,
                                                   const float* __restrict__ W3,
                                                   unsigned short* __restrict__ T1,
                                                   unsigned short* __restrict__ T2,
                                                   unsigned short* __restrict__ T3) {
  int w = blockIdx.x >> 6;
  int i = (blockIdx.x & 63) * 256 + threadIdx.x;  // 0..16383
  const float* W = (w == 0) ? W1 : (w == 1) ? W2 : W3;
  unsigned short* T = (w == 0) ? T1 : (w == 1) ? T2 : T3;
  int n = i >> 7, k = i & 127;
  T[n * 128 + k] = (unsigned short)bf16rne(W[k * 128 + n]);
}

// ---------------- CSR build, no global atomics ----------------
__global__ __launch_bounds__(1024) void hist_kernel(const int* __restrict__ src,
                                                    const int* __restrict__ dst,
                                                    int* __restrict__ partial_dst,
                                                    int* __restrict__ partial_src) {
  __shared__ int hd[NPR];
  __shared__ int hs[NPR];
  int tid = threadIdx.x;
  int c = blockIdx.x >> 3;
  int r = blockIdx.x & 7;
  int base = r * NPR;
  for (int i = tid; i < NPR; i += 1024) { hd[i] = 0; hs[i] = 0; }
  __syncthreads();
  int e0 = c * EPC;
  for (int i = tid; i < EPC; i += 1024) {
    int d = dst[e0 + i];
    int s = src[e0 + i];
    unsigned dr = (unsigned)(d - base);
    unsigned sr = (unsigned)(s - base);
    if (dr < NPR) atomicAdd(&hd[dr], 1);
    if (sr < NPR) atomicAdd(&hs[sr], 1);
  }
  __syncthreads();
  for (int i = tid; i < NPR; i += 1024) {
    partial_dst[c * NN + base + i] = hd[i];
    partial_src[c * NN + base + i] = hs[i];
  }
}

__global__ __launch_bounds__(256) void reduce_kernel(int* __restrict__ partial_dst,
                                                     const int* __restrict__ partial_src,
                                                     int* __restrict__ degtmp,
                                                     int* __restrict__ deg_out, int N) {
  int d = blockIdx.x * 256 + threadIdx.x;
  if (d >= N) return;
  int run = 0;
#pragma unroll
  for (int c = 0; c < CH; ++c) {
    int v = partial_dst[c * NN + d];
    partial_dst[c * NN + d] = run;
    run += v;
  }
  degtmp[d] = run;
  int ro = 0;
#pragma unroll
  for (int c = 0; c < CH; ++c) ro += partial_src[c * NN + d];
  deg_out[d] = ro;
}

// ---------------- 3-phase exclusive scan over degtmp -> row_ptr --------------

__device__ __forceinline__ int block_excl_scan(int v, int* wsum) {
  int lane = threadIdx.x & 63;
  int w = threadIdx.x >> 6;
  int incl = v;
#pragma unroll
  for (int off = 1; off < 64; off <<= 1) {
    int t = __shfl_up(incl, off);
    if (lane >= off) incl += t;
  }
  if (lane == 63) wsum[w] = incl;
  __syncthreads();
  int wo = 0;
#pragma unroll
  for (int j = 0; j < 4; ++j)
    if (j < w) wo += wsum[j];
  return wo + incl - v;
}

__global__ __launch_bounds__(256) void scan1(const int* __restrict__ deg,
                                             int* __restrict__ partials, int N) {
  __shared__ int wsum[4];
  int i = blockIdx.x * 256 + threadIdx.x;
  int v = (i < N) ? deg[i] : 0;
  int excl = block_excl_scan(v, wsum);
  if (threadIdx.x == 255) partials[blockIdx.x] = excl + v;
}

__global__ __launch_bounds__(256) void scan2(int* __restrict__ partials, int nb) {
  __shared__ int wsum[4];
  int v = (threadIdx.x < nb) ? partials[threadIdx.x] : 0;
  int excl = block_excl_scan(v, wsum);
  if (threadIdx.x < nb) partials[threadIdx.x] = excl;
}

__global__ __launch_bounds__(256) void scan3(const int* __restrict__ deg,
                                             const int* __restrict__ partials,
                                             int* __restrict__ row_ptr, int N) {
  __shared__ int wsum[4];
  int i = blockIdx.x * 256 + threadIdx.x;
  int v = (i < N) ? deg[i] : 0;
  int excl = block_excl_scan(v, wsum);
  if (i < N) row_ptr[i] = partials[blockIdx.x] + excl;
  if (blockIdx.x == gridDim.x - 1 && threadIdx.x == 0) row_ptr[N] = NE;
}

__global__ __launch_bounds__(1024) void fill_kernel(const int* __restrict__ src,
                                                    const int* __restrict__ dst,
                                                    const int* __restrict__ row_ptr,
                                                    const int* __restrict__ partial_dst,
                                                    int* __restrict__ csr_src) {
  __shared__ int cur[NPR];
  int tid = threadIdx.x;
  int c = blockIdx.x >> 3;
  int r = blockIdx.x & 7;
  int base = r * NPR;
  for (int i = tid; i < NPR; i += 1024)
    cur[i] = row_ptr[base + i] + partial_dst[c * NN + base + i];
  __syncthreads();
  int e0 = c * EPC;
  for (int i = tid; i < EPC; i += 1024) {
    int d = dst[e0 + i];
    unsigned dr = (unsigned)(d - base);
    if (dr < NPR) {
      int pos = atomicAdd(&cur[dr], 1);
      csr_src[pos] = src[e0 + i];
    }
  }
}

// ---------------- aggregation: one wave per node, quarter-wave per edge ------
// bf16 in, f32 accumulate, bf16 out. MODE 0: sage. MODE 1: gcn rsqrt.
__device__ __forceinline__ void bacc(float* a, uint4 u) {
  a[0] += __uint_as_float(u.x << 16);
  a[1] += __uint_as_float(u.x & 0xffff0000u);
  a[2] += __uint_as_float(u.y << 16);
  a[3] += __uint_as_float(u.y & 0xffff0000u);
  a[4] += __uint_as_float(u.z << 16);
  a[5] += __uint_as_float(u.z & 0xffff0000u);
  a[6] += __uint_as_float(u.w << 16);
  a[7] += __uint_as_float(u.w & 0xffff0000u);
}

template <int MODE>
__global__ __launch_bounds__(256) void agg_kernel(const unsigned short* __restrict__ hb,
                                                  const int* __restrict__ row_ptr,
                                                  const int* __restrict__ csr_src,
                                                  unsigned short* __restrict__ outb, int N) {
  int wid = blockIdx.x * 4 + (threadIdx.x >> 6);
  int lane = threadIdx.x & 63;
  if (wid >= N) return;
  int start = row_ptr[wid];
  int end = row_ptr[wid + 1];
  int q = lane >> 4;    // 0..3: which edge in the 4-group
  int col = lane & 15;  // 16B granule within row
  float a0[8] = {0, 0, 0, 0, 0, 0, 0, 0};
  float a1[8] = {0, 0, 0, 0, 0, 0, 0, 0};
  float a2[8] = {0, 0, 0, 0, 0, 0, 0, 0};
  float a3[8] = {0, 0, 0, 0, 0, 0, 0, 0};
  int e = start;
  for (; e + 16 <= end; e += 16) {
    int i0 = csr_src[e + q];
    int i1 = csr_src[e + 4 + q];
    int i2 = csr_src[e + 8 + q];
    int i3 = csr_src[e + 12 + q];
    uint4 u0 = ((const uint4*)(hb + (size_t)i0 * D))[col];
    uint4 u1 = ((const uint4*)(hb + (size_t)i1 * D))[col];
    uint4 u2 = ((const uint4*)(hb + (size_t)i2 * D))[col];
    uint4 u3 = ((const uint4*)(hb + (size_t)i3 * D))[col];
    bacc(a0, u0);
    bacc(a1, u1);
    bacc(a2, u2);
    bacc(a3, u3);
  }
  for (; e + 4 <= end; e += 4) {
    int i0 = csr_src[e + q];
    uint4 u0 = ((const uint4*)(hb + (size_t)i0 * D))[col];
    bacc(a0, u0);
  }
  if (q < end - e) {
    int i0 = csr_src[e + q];
    uint4 u0 = ((const uint4*)(hb + (size_t)i0 * D))[col];
    bacc(a0, u0);
  }
#pragma unroll
  for (int j = 0; j < 8; ++j) a0[j] = (a0[j] + a1[j]) + (a2[j] + a3[j]);
#pragma unroll
  for (int j = 0; j < 8; ++j) {
    a0[j] += __shfl_xor(a0[j], 16);
    a0[j] += __shfl_xor(a0[j], 32);
  }
  int indeg = end - start;
  if (MODE == 0) {
    uint4 s = ((const uint4*)(hb + (size_t)wid * D))[col];
    float sf[8] = {0, 0, 0, 0, 0, 0, 0, 0};
    bacc(sf, s);
    float inv = 1.0f / (float)(indeg + 1);
#pragma unroll
    for (int j = 0; j < 8; ++j) a0[j] = (a0[j] + sf[j]) * inv;
  } else {
    float sc = rsqrtf(fmaxf((float)indeg, 1.0f));
#pragma unroll
    for (int j = 0; j < 8; ++j) a0[j] *= sc;
  }
  if (q == 0) {
    uint4 p;
    p.x = packbf(a0[0], a0[1]);
    p.y = packbf(a0[2], a0[3]);
    p.z = packbf(a0[4], a0[5]);
    p.w = packbf(a0[6], a0[7]);
    ((uint4*)(outb + (size_t)wid * D))[col] = p;
  }
}

// ---------------- MFMA GEMM: [N x 128](bf16) @ [128 x 128] + bias ------------
// 256 thr = 4 waves; block tile 64 rows; wave tile 16 rows x 128 cols.
// mfma_f32_16x16x32_bf16: A[m=lane&15][k=quad*8+j], B[k=quad*8+j][n=lane&15],
// C/D: col=lane&15, row=quad*4+reg. WT (=W^T, [n][k]) staged in LDS, row
// stride 136 ushorts (+16B pad -> 2-way bank conflict = free).
// MODE 1: scale rows by rsqrt(max(deg_out,1)). OUT_BF 1: write bf16 table.
template <int MODE, int OUT_BF>
__global__ __launch_bounds__(256) void mgemm_kernel(const unsigned short* __restrict__ A,
                                                    const unsigned short* __restrict__ WT,
                                                    const float* __restrict__ bias,
                                                    const int* __restrict__ deg_out,
                                                    float* __restrict__ outf,
                                                    unsigned short* __restrict__ outb, int N) {
  __shared__ unsigned short sWT[128 * 136];
  int tid = threadIdx.x;
  for (int g = tid; g < 2048; g += 256) {
    int n = g >> 4, c = g & 15;
    uint4 v = ((const uint4*)WT)[g];
    *(uint4*)&sWT[n * 136 + c * 8] = v;
  }
  int wv = tid >> 6;
  int lane = tid & 63;
  int q = lane >> 4;
  int ln = lane & 15;
  int row0 = blockIdx.x * 64 + wv * 16;
  int arow = row0 + ln;
  if (arow >= N) arow = 0;  // clamp; stores are guarded
  const unsigned short* Ar = A + (size_t)arow * 128 + q * 8;
  bf16x8 af0 = *(const bf16x8*)(Ar + 0);
  bf16x8 af1 = *(const bf16x8*)(Ar + 32);
  bf16x8 af2 = *(const bf16x8*)(Ar + 64);
  bf16x8 af3 = *(const bf16x8*)(Ar + 96);
  f32x4 acc[8];
#pragma unroll
  for (int t = 0; t < 8; ++t) acc[t] = (f32x4){0.f, 0.f, 0.f, 0.f};
  __syncthreads();
#pragma unroll
  for (int t = 0; t < 8; ++t) {
    const unsigned short* Wr = &sWT[(t * 16 + ln) * 136 + q * 8];
    bf16x8 b0 = *(const bf16x8*)(Wr + 0);
    bf16x8 b1 = *(const bf16x8*)(Wr + 32);
    bf16x8 b2 = *(const bf16x8*)(Wr + 64);
    bf16x8 b3 = *(const bf16x8*)(Wr + 96);
    acc[t] = __builtin_amdgcn_mfma_f32_16x16x32_bf16(af0, b0, acc[t], 0, 0, 0);
    acc[t] = __builtin_amdgcn_mfma_f32_16x16x32_bf16(af1, b1, acc[t], 0, 0, 0);
    acc[t] = __builtin_amdgcn_mfma_f32_16x16x32_bf16(af2, b2, acc[t], 0, 0, 0);
    acc[t] = __builtin_amdgcn_mfma_f32_16x16x32_bf16(af3, b3, acc[t], 0, 0, 0);
  }
  float scl[4];
#pragma unroll
  for (int r = 0; r < 4; ++r) {
    scl[r] = 1.0f;
    if (MODE == 1) {
      int row = row0 + q * 4 + r;
      int rr = (row < N) ? row : 0;
      scl[r] = rsqrtf(fmaxf((float)deg_out[rr], 1.0f));
    }
  }
#pragma unroll
  for (int t = 0; t < 8; ++t) {
    float b = bias[t * 16 + ln];
#pragma unroll
    for (int r = 0; r < 4; ++r) {
      int row = row0 + q * 4 + r;
      if (row < N) {
        float v = (acc[t][r] + b) * scl[r];
        if (OUT_BF)
          outb[(size_t)row * 128 + t * 16 + ln] = (unsigned short)bf16rne(v);
        else
          outf[(size_t)row * 128 + t * 16 + ln] = v;
      }
    }
  }
}

// ---------------- launcher ----------------

extern "C" void kernel_launch(void* const* d_in, const int* in_sizes, int n_in,
                              void* d_out, int out_size, void* d_ws, size_t ws_size,
                              hipStream_t stream) {
  const float* x = (const float*)d_in[0];
  const float* W1 = (const float*)d_in[1];
  const float* b1 = (const float*)d_in[2];
  const float* W2 = (const float*)d_in[3];
  const float* b2 = (const float*)d_in[4];
  const float* W3 = (const float*)d_in[5];
  const float* b3 = (const float*)d_in[6];
  const int* src = (const int*)d_in[7];
  const int* dst = (const int*)d_in[8];
  float* out = (float*)d_out;

  const int N = NN, E = NE;

  // workspace layout (~56 MB)
  unsigned short* hbf = (unsigned short*)d_ws;             // N*D bf16
  unsigned short* aggB = hbf + (size_t)N * D;              // N*D bf16
  unsigned short* WT1 = aggB + (size_t)N * D;              // 128*128 bf16
  unsigned short* WT2 = WT1 + D * D;                       // 128*128 bf16
  unsigned short* WT3 = WT2 + D * D;                       // 128*128 bf16
  int* partial_dst = (int*)(WT3 + D * D);                  // CH*N
  int* partial_src = partial_dst + (size_t)CH * N;         // CH*N
  int* degtmp = partial_src + (size_t)CH * N;              // N
  int* deg_out = degtmp + N;                               // N
  int* row_ptr = deg_out + N;                              // N+1
  int* partials = row_ptr + N + 1;                         // 256
  int* csr_src = partials + 256;                           // E

  const int scanBlocks = (N + 255) / 256;  // 196

  cvt_kernel<<<(N * D / 4 + 255) / 256, 256, 0, stream>>>(x, hbf, N * D / 4);
  wcvt_kernel<<<192, 256, 0, stream>>>(W1, W2, W3, WT1, WT2, WT3);
  hist_kernel<<<CH * RG, 1024, 0, stream>>>(src, dst, partial_dst, partial_src);
  reduce_kernel<<<scanBlocks, 256, 0, stream>>>(partial_dst, partial_src, degtmp, deg_out, N);
  scan1<<<scanBlocks, 256, 0, stream>>>(degtmp, partials, N);
  scan2<<<1, 256, 0, stream>>>(partials, scanBlocks);
  scan3<<<scanBlocks, 256, 0, stream>>>(degtmp, partials, row_ptr, N);
  fill_kernel<<<CH * RG, 1024, 0, stream>>>(src, dst, row_ptr, partial_dst, csr_src);

  int aggBlocks = (N + 3) / 4;
  int gemmBlocks = (N + 63) / 64;

  // layer 1: sage(x)
  agg_kernel<0><<<aggBlocks, 256, 0, stream>>>(hbf, row_ptr, csr_src, aggB, N);
  mgemm_kernel<0, 1><<<gemmBlocks, 256, 0, stream>>>(aggB, WT1, b1, deg_out, nullptr, hbf, N);
  // layer 2: sage(h1); fold norm_out for layer 3 into epilogue
  agg_kernel<0><<<aggBlocks, 256, 0, stream>>>(hbf, row_ptr, csr_src, aggB, N);
  mgemm_kernel<1, 1><<<gemmBlocks, 256, 0, stream>>>(aggB, WT2, b2, deg_out, nullptr, hbf, N);
  // layer 3: gcn: (agg(h2*norm_out) * norm_in) @ W3 + b3
  agg_kernel<1><<<aggBlocks, 256, 0, stream>>>(hbf, row_ptr, csr_src, aggB, N);
  mgemm_kernel<0, 0><<<gemmBlocks, 256, 0, stream>>>(aggB, WT3, b3, deg_out, out, nullptr, N);
}

// Round 6
// 273.047 us; speedup vs baseline: 2.0029x; 1.0431x over previous
//
#include <hip/hip_runtime.h>

#define NN 50000
#define NE 800000
#define D 128

#define CH 64              // edge chunks
#define EPC (NE / CH)      // 12500 edges per chunk
#define RG 8               // node ranges
#define NPR (NN / RG)      // 6250 nodes per range
#define CSRCAP (NE + 16 * NN)

typedef short bf16x8 __attribute__((ext_vector_type(8)));
typedef float f32x4 __attribute__((ext_vector_type(4)));

// ---------------- bf16 helpers ----------------

__device__ __forceinline__ unsigned bf16rne(float f) {
  unsigned u = __float_as_uint(f);
  return (u + 0x7fffu + ((u >> 16) & 1u)) >> 16;
}
__device__ __forceinline__ unsigned packbf(float lo, float hi) {
  return bf16rne(lo) | (bf16rne(hi) << 16);
}

// fused: x->bf16 (blocks 0..6249), W^T bf16 x3 (blocks 6250..6441), zero row NN
__global__ __launch_bounds__(256) void cvtw_kernel(const float* __restrict__ x,
                                                   const float* __restrict__ W1,
                                                   const float* __restrict__ W2,
                                                   const float* __restrict__ W3,
                                                   unsigned short* __restrict__ hbf,
                                                   unsigned short* __restrict__ T1,
                                                   unsigned short* __restrict__ T2,
                                                   unsigned short* __restrict__ T3) {
  int b = blockIdx.x;
  int tid = threadIdx.x;
  if (b < 6250) {
    int i = b * 256 + tid;  // n4 = NN*D/4 = 1.6M exactly
    float4 v = ((const float4*)x)[i];
    uint2 p;
    p.x = packbf(v.x, v.y);
    p.y = packbf(v.z, v.w);
    ((uint2*)hbf)[i] = p;
  } else if (b < 6442) {
    int g = b - 6250;
    int w = g >> 6;
    int i = (g & 63) * 256 + tid;  // 0..16383
    const float* W = (w == 0) ? W1 : (w == 1) ? W2 : W3;
    unsigned short* T = (w == 0) ? T1 : (w == 1) ? T2 : T3;
    int n = i >> 7, k = i & 127;
    T[n * 128 + k] = (unsigned short)bf16rne(W[k * 128 + n]);
  } else {
    if (tid < 16) ((uint4*)(hbf + (size_t)NN * D))[tid] = make_uint4(0, 0, 0, 0);
  }
}

// ---------------- CSR build, no global atomics ----------------
__global__ __launch_bounds__(1024) void hist_kernel(const int* __restrict__ src,
                                                    const int* __restrict__ dst,
                                                    int* __restrict__ partial_dst,
                                                    int* __restrict__ partial_src) {
  __shared__ int hd[NPR];
  __shared__ int hs[NPR];
  int tid = threadIdx.x;
  int c = blockIdx.x >> 3;
  int r = blockIdx.x & 7;
  int base = r * NPR;
  for (int i = tid; i < NPR; i += 1024) { hd[i] = 0; hs[i] = 0; }
  __syncthreads();
  int e0 = c * EPC;
  for (int i = tid; i < EPC; i += 1024) {
    int d = dst[e0 + i];
    int s = src[e0 + i];
    unsigned dr = (unsigned)(d - base);
    unsigned sr = (unsigned)(s - base);
    if (dr < NPR) atomicAdd(&hd[dr], 1);
    if (sr < NPR) atomicAdd(&hs[sr], 1);
  }
  __syncthreads();
  for (int i = tid; i < NPR; i += 1024) {
    partial_dst[c * NN + base + i] = hd[i];
    partial_src[c * NN + base + i] = hs[i];
  }
}

__device__ __forceinline__ int block_excl_scan(int v, int* wsum) {
  int lane = threadIdx.x & 63;
  int w = threadIdx.x >> 6;
  int incl = v;
#pragma unroll
  for (int off = 1; off < 64; off <<= 1) {
    int t = __shfl_up(incl, off);
    if (lane >= off) incl += t;
  }
  if (lane == 63) wsum[w] = incl;
  __syncthreads();
  int wo = 0;
#pragma unroll
  for (int j = 0; j < 4; ++j)
    if (j < w) wo += wsum[j];
  return wo + incl - v;
}

// fused reduce + scan phase 1: chunk-prefix partial_dst in place, true in-deg
// -> degtmp, out-deg -> deg_out, block-exclusive-scan of PADDED degree
// (ceil16) -> row_ptr (local), block totals -> partials.
__global__ __launch_bounds__(256) void degscan_kernel(int* __restrict__ partial_dst,
                                                      const int* __restrict__ partial_src,
                                                      int* __restrict__ degtmp,
                                                      int* __restrict__ deg_out,
                                                      int* __restrict__ row_ptr,
                                                      int* __restrict__ partials, int N) {
  __shared__ int wsum[4];
  int d = blockIdx.x * 256 + threadIdx.x;
  int run = 0;
  if (d < N) {
#pragma unroll
    for (int c = 0; c < CH; ++c) {
      int v = partial_dst[c * NN + d];
      partial_dst[c * NN + d] = run;
      run += v;
    }
    degtmp[d] = run;
    int ro = 0;
#pragma unroll
    for (int c = 0; c < CH; ++c) ro += partial_src[c * NN + d];
    deg_out[d] = ro;
  }
  int pad = (run + 15) & ~15;
  int excl = block_excl_scan(pad, wsum);
  if (d < N) row_ptr[d] = excl;
  if (threadIdx.x == 255) partials[blockIdx.x] = excl + pad;
}

__global__ __launch_bounds__(256) void scan2(int* __restrict__ partials,
                                             int* __restrict__ row_ptr, int nb, int N) {
  __shared__ int wsum[4];
  int v = (threadIdx.x < nb) ? partials[threadIdx.x] : 0;
  int excl = block_excl_scan(v, wsum);
  if (threadIdx.x < nb) partials[threadIdx.x] = excl;
  if (threadIdx.x == nb - 1) row_ptr[N] = excl + v;
}

__global__ __launch_bounds__(256) void scan3(int* __restrict__ row_ptr,
                                             const int* __restrict__ partials, int N) {
  int i = blockIdx.x * 256 + threadIdx.x;
  if (i < N) row_ptr[i] += partials[blockIdx.x];
}

__global__ __launch_bounds__(1024) void fill_kernel(const int* __restrict__ src,
                                                    const int* __restrict__ dst,
                                                    const int* __restrict__ row_ptr,
                                                    const int* __restrict__ partial_dst,
                                                    int* __restrict__ csr_src) {
  __shared__ int cur[NPR];
  int tid = threadIdx.x;
  int c = blockIdx.x >> 3;
  int r = blockIdx.x & 7;
  int base = r * NPR;
  for (int i = tid; i < NPR; i += 1024)
    cur[i] = row_ptr[base + i] + partial_dst[c * NN + base + i];
  __syncthreads();
  int e0 = c * EPC;
  for (int i = tid; i < EPC; i += 1024) {
    int d = dst[e0 + i];
    unsigned dr = (unsigned)(d - base);
    if (dr < NPR) {
      int pos = atomicAdd(&cur[dr], 1);
      csr_src[pos] = src[e0 + i];
    }
  }
}

// write dummy index NN into each row's pad tail [row_ptr[i]+deg, row_ptr[i+1])
__global__ __launch_bounds__(256) void pad_kernel(const int* __restrict__ row_ptr,
                                                  const int* __restrict__ degtmp,
                                                  int* __restrict__ csr_src, int N) {
  int i = blockIdx.x * 256 + threadIdx.x;
  if (i >= N) return;
  int s = row_ptr[i] + degtmp[i];
  int e = row_ptr[i + 1];
  for (int j = s; j < e; ++j) csr_src[j] = NN;
}

// ---------------- aggregation: one wave per node, quarter-wave per edge ------
// Rows padded to x16 edges -> single branch-free 16-deep pipelined loop.
// bf16 in, f32 accumulate, bf16 out. MODE 0: sage. MODE 1: gcn rsqrt.
__device__ __forceinline__ void bacc(float* a, uint4 u) {
  a[0] += __uint_as_float(u.x << 16);
  a[1] += __uint_as_float(u.x & 0xffff0000u);
  a[2] += __uint_as_float(u.y << 16);
  a[3] += __uint_as_float(u.y & 0xffff0000u);
  a[4] += __uint_as_float(u.z << 16);
  a[5] += __uint_as_float(u.z & 0xffff0000u);
  a[6] += __uint_as_float(u.w << 16);
  a[7] += __uint_as_float(u.w & 0xffff0000u);
}

template <int MODE>
__global__ __launch_bounds__(256) void agg_kernel(const unsigned short* __restrict__ hb,
                                                  const int* __restrict__ row_ptr,
                                                  const int* __restrict__ csr_src,
                                                  const int* __restrict__ degtmp,
                                                  unsigned short* __restrict__ outb, int N) {
  int wid = blockIdx.x * 4 + (threadIdx.x >> 6);
  int lane = threadIdx.x & 63;
  if (wid >= N) return;
  int start = row_ptr[wid];
  int iters = (row_ptr[wid + 1] - start) >> 4;
  int q = lane >> 4;    // 0..3: which edge in the 4-group
  int col = lane & 15;  // 16B granule within row
  float a0[8] = {0, 0, 0, 0, 0, 0, 0, 0};
  float a1[8] = {0, 0, 0, 0, 0, 0, 0, 0};
  float a2[8] = {0, 0, 0, 0, 0, 0, 0, 0};
  float a3[8] = {0, 0, 0, 0, 0, 0, 0, 0};
  const int* ce = csr_src + start + q;
  for (int it = 0; it < iters; ++it, ce += 16) {
    int i0 = ce[0];
    int i1 = ce[4];
    int i2 = ce[8];
    int i3 = ce[12];
    uint4 u0 = ((const uint4*)(hb + (size_t)i0 * D))[col];
    uint4 u1 = ((const uint4*)(hb + (size_t)i1 * D))[col];
    uint4 u2 = ((const uint4*)(hb + (size_t)i2 * D))[col];
    uint4 u3 = ((const uint4*)(hb + (size_t)i3 * D))[col];
    bacc(a0, u0);
    bacc(a1, u1);
    bacc(a2, u2);
    bacc(a3, u3);
  }
#pragma unroll
  for (int j = 0; j < 8; ++j) a0[j] = (a0[j] + a1[j]) + (a2[j] + a3[j]);
#pragma unroll
  for (int j = 0; j < 8; ++j) {
    a0[j] += __shfl_xor(a0[j], 16);
    a0[j] += __shfl_xor(a0[j], 32);
  }
  int indeg = degtmp[wid];
  if (MODE == 0) {
    uint4 s = ((const uint4*)(hb + (size_t)wid * D))[col];
    float sf[8] = {0, 0, 0, 0, 0, 0, 0, 0};
    bacc(sf, s);
    float inv = 1.0f / (float)(indeg + 1);
#pragma unroll
    for (int j = 0; j < 8; ++j) a0[j] = (a0[j] + sf[j]) * inv;
  } else {
    float sc = rsqrtf(fmaxf((float)indeg, 1.0f));
#pragma unroll
    for (int j = 0; j < 8; ++j) a0[j] *= sc;
  }
  if (q == 0) {
    uint4 p;
    p.x = packbf(a0[0], a0[1]);
    p.y = packbf(a0[2], a0[3]);
    p.z = packbf(a0[4], a0[5]);
    p.w = packbf(a0[6], a0[7]);
    ((uint4*)(outb + (size_t)wid * D))[col] = p;
  }
}

// ---------------- MFMA GEMM: [N x 128](bf16) @ [128 x 128] + bias ------------
// 256 thr = 4 waves; block tile 64 rows; wave tile 16 rows x 128 cols.
// MODE 1: scale rows by rsqrt(max(deg_out,1)). OUT_BF 1: write bf16 table.
template <int MODE, int OUT_BF>
__global__ __launch_bounds__(256) void mgemm_kernel(const unsigned short* __restrict__ A,
                                                    const unsigned short* __restrict__ WT,
                                                    const float* __restrict__ bias,
                                                    const int* __restrict__ deg_out,
                                                    float* __restrict__ outf,
                                                    unsigned short* __restrict__ outb, int N) {
  __shared__ unsigned short sWT[128 * 136];
  int tid = threadIdx.x;
  for (int g = tid; g < 2048; g += 256) {
    int n = g >> 4, c = g & 15;
    uint4 v = ((const uint4*)WT)[g];
    *(uint4*)&sWT[n * 136 + c * 8] = v;
  }
  int wv = tid >> 6;
  int lane = tid & 63;
  int q = lane >> 4;
  int ln = lane & 15;
  int row0 = blockIdx.x * 64 + wv * 16;
  int arow = row0 + ln;
  if (arow >= N) arow = 0;  // clamp; stores are guarded
  const unsigned short* Ar = A + (size_t)arow * 128 + q * 8;
  bf16x8 af0 = *(const bf16x8*)(Ar + 0);
  bf16x8 af1 = *(const bf16x8*)(Ar + 32);
  bf16x8 af2 = *(const bf16x8*)(Ar + 64);
  bf16x8 af3 = *(const bf16x8*)(Ar + 96);
  f32x4 acc[8];
#pragma unroll
  for (int t = 0; t < 8; ++t) acc[t] = (f32x4){0.f, 0.f, 0.f, 0.f};
  __syncthreads();
#pragma unroll
  for (int t = 0; t < 8; ++t) {
    const unsigned short* Wr = &sWT[(t * 16 + ln) * 136 + q * 8];
    bf16x8 b0 = *(const bf16x8*)(Wr + 0);
    bf16x8 b1 = *(const bf16x8*)(Wr + 32);
    bf16x8 b2 = *(const bf16x8*)(Wr + 64);
    bf16x8 b3 = *(const bf16x8*)(Wr + 96);
    acc[t] = __builtin_amdgcn_mfma_f32_16x16x32_bf16(af0, b0, acc[t], 0, 0, 0);
    acc[t] = __builtin_amdgcn_mfma_f32_16x16x32_bf16(af1, b1, acc[t], 0, 0, 0);
    acc[t] = __builtin_amdgcn_mfma_f32_16x16x32_bf16(af2, b2, acc[t], 0, 0, 0);
    acc[t] = __builtin_amdgcn_mfma_f32_16x16x32_bf16(af3, b3, acc[t], 0, 0, 0);
  }
  float scl[4];
#pragma unroll
  for (int r = 0; r < 4; ++r) {
    scl[r] = 1.0f;
    if (MODE == 1) {
      int row = row0 + q * 4 + r;
      int rr = (row < N) ? row : 0;
      scl[r] = rsqrtf(fmaxf((float)deg_out[rr], 1.0f));
    }
  }
#pragma unroll
  for (int t = 0; t < 8; ++t) {
    float b = bias[t * 16 + ln];
#pragma unroll
    for (int r = 0; r < 4; ++r) {
      int row = row0 + q * 4 + r;
      if (row < N) {
        float v = (acc[t][r] + b) * scl[r];
        if (OUT_BF)
          outb[(size_t)row * 128 + t * 16 + ln] = (unsigned short)bf16rne(v);
        else
          outf[(size_t)row * 128 + t * 16 + ln] = v;
      }
    }
  }
}

// ---------------- launcher ----------------

extern "C" void kernel_launch(void* const* d_in, const int* in_sizes, int n_in,
                              void* d_out, int out_size, void* d_ws, size_t ws_size,
                              hipStream_t stream) {
  const float* x = (const float*)d_in[0];
  const float* W1 = (const float*)d_in[1];
  const float* b1 = (const float*)d_in[2];
  const float* W2 = (const float*)d_in[3];
  const float* b2 = (const float*)d_in[4];
  const float* W3 = (const float*)d_in[5];
  const float* b3 = (const float*)d_in[6];
  const int* src = (const int*)d_in[7];
  const int* dst = (const int*)d_in[8];
  float* out = (float*)d_out;

  const int N = NN;

  // workspace layout (~58 MB)
  unsigned short* hbf = (unsigned short*)d_ws;             // (NN+1)*D bf16
  unsigned short* aggB = hbf + (size_t)(NN + 1) * D;       // NN*D bf16
  unsigned short* WT1 = aggB + (size_t)NN * D;             // 128*128 bf16
  unsigned short* WT2 = WT1 + D * D;
  unsigned short* WT3 = WT2 + D * D;
  int* partial_dst = (int*)(WT3 + D * D);                  // CH*NN
  int* partial_src = partial_dst + (size_t)CH * NN;        // CH*NN
  int* degtmp = partial_src + (size_t)CH * NN;             // NN
  int* deg_out = degtmp + NN;                              // NN
  int* row_ptr = deg_out + NN;                             // NN+1
  int* partials = row_ptr + NN + 1;                        // 256
  int* csr_src = partials + 256;                           // CSRCAP

  const int scanBlocks = (N + 255) / 256;  // 196

  cvtw_kernel<<<6443, 256, 0, stream>>>(x, W1, W2, W3, hbf, WT1, WT2, WT3);
  hist_kernel<<<CH * RG, 1024, 0, stream>>>(src, dst, partial_dst, partial_src);
  degscan_kernel<<<scanBlocks, 256, 0, stream>>>(partial_dst, partial_src, degtmp,
                                                 deg_out, row_ptr, partials, N);
  scan2<<<1, 256, 0, stream>>>(partials, row_ptr, scanBlocks, N);
  scan3<<<scanBlocks, 256, 0, stream>>>(row_ptr, partials, N);
  fill_kernel<<<CH * RG, 1024, 0, stream>>>(src, dst, row_ptr, partial_dst, csr_src);
  pad_kernel<<<scanBlocks, 256, 0, stream>>>(row_ptr, degtmp, csr_src, N);

  int aggBlocks = (N + 3) / 4;
  int gemmBlocks = (N + 63) / 64;

  // layer 1: sage(x)
  agg_kernel<0><<<aggBlocks, 256, 0, stream>>>(hbf, row_ptr, csr_src, degtmp, aggB, N);
  mgemm_kernel<0, 1><<<gemmBlocks, 256, 0, stream>>>(aggB, WT1, b1, deg_out, nullptr, hbf, N);
  // layer 2: sage(h1); fold norm_out for layer 3 into epilogue
  agg_kernel<0><<<aggBlocks, 256, 0, stream>>>(hbf, row_ptr, csr_src, degtmp, aggB, N);
  mgemm_kernel<1, 1><<<gemmBlocks, 256, 0, stream>>>(aggB, WT2, b2, deg_out, nullptr, hbf, N);
  // layer 3: gcn: (agg(h2*norm_out) * norm_in) @ W3 + b3
  agg_kernel<1><<<aggBlocks, 256, 0, stream>>>(hbf, row_ptr, csr_src, degtmp, aggB, N);
  mgemm_kernel<0, 0><<<gemmBlocks, 256, 0, stream>>>(aggB, WT3, b3, deg_out, out, nullptr, N);
}